// Round 3
// baseline (236.764 us; speedup 1.0000x reference)
//
#include <hip/hip_runtime.h>
#include <math.h>

#define NR 8
#define NB 8
#define NH 32
#define NKVH 8
#define NG 4
#define ND 128
#define NDV 128
#define NPAGE 2048
#define CCHUNK 256
#define NSP 8                 // chunks per (r,b): 2048/256
#define NPART (NR*NSP)        // 64 partials
#define KSTR (NKVH*ND)        // 1024 floats per page
#define PSTRIDE (NB*NKVH*NG)  // 2048 rows per partial slot
#define QSCALE 0.088388347648318447f
#define KLD 129               // padded LDS K row stride (floats, odd)

__global__ __launch_bounds__(256, 2) void attn_partial(
    const float* __restrict__ q,
    const float* __restrict__ k_cache,
    const float* __restrict__ v_cache,
    const int* __restrict__ kv_lens,
    const int* __restrict__ block_table,
    float* __restrict__ ws_out,   // [NPART][NB][NKVH][NG][NDV]
    float* __restrict__ ws_lse)   // [NPART][NB][NKVH][NG]
{
  // XCD swizzle: all 64 blocks of one (r,b) share bid&7 -> same XCD L2.
  const int bid  = blockIdx.x;
  const int xcd  = bid & 7;
  const int t0   = bid >> 3;
  const int gg   = t0 >> 6;
  const int inner= t0 & 63;
  const int gr   = (gg << 3) | xcd;   // (r,b) group 0..63
  const int r    = gr >> 3;
  const int b    = gr & 7;
  const int kvh  = inner >> 3;
  const int sp   = inner & 7;

  const int tid  = threadIdx.x;
  const int wid  = tid >> 6;
  const int lane = tid & 63;

  const int len = kv_lens[r * NB + b];
  const int lo  = sp * CCHUNK;
  const int pi  = r * NSP + sp;
  const size_t pbase = (((size_t)pi * NB + b) * NKVH + kvh) * NG;

  if (lo >= len) {               // whole block empty: sentinel, uniform exit
    if (tid < NG) ws_lse[pbase + tid] = -1e30f;
    return;
  }
  const int hi = min(len, lo + CCHUNK);

  __shared__ float Kl[4][32][KLD];   // per-wave K tile
  __shared__ float ql[NG][KLD];      // scaled q
  __shared__ float Pl[4][32][NG];    // per-wave p values
  __shared__ float Ml[4][NG], Ll[4][NG];
  __shared__ float Acc[4][NG][NDV];
  __shared__ float Mg[NG], Lg[NG];

  // cooperative q load (+scale): thread -> (h, 2 floats)
  {
    const int h  = tid >> 6;
    const int d0 = (tid & 63) * 2;
    const float* qp = q + (size_t)(b * NH + kvh * NG + h) * ND + d0;
    ql[h][d0]     = qp[0] * QSCALE;
    ql[h][d0 + 1] = qp[1] * QSCALE;
  }
  __syncthreads();

  const int tq = lane >> 2;     // 0..15: owns rows {tq, tq+16}
  const int dq = lane & 3;      // d-quarter
  const int h5 = lane >> 5;     // staging: row-pair half
  const int c5 = lane & 31;     // staging: float4 column

  const int* bt = block_table + (r * NB + b) * NPAGE;
  const float* Kbase = k_cache + (size_t)r * NPAGE * KSTR + kvh * ND;
  const float* Vbase = v_cache + (size_t)r * NPAGE * KSTR + kvh * NDV + 2 * lane;

  float M[NG], Lr[NG];
  float2 acc2[NG];
#pragma unroll
  for (int h = 0; h < NG; ++h) {
    M[h] = -INFINITY; Lr[h] = 0.f;
    acc2[h].x = 0.f; acc2[h].y = 0.f;
  }

  for (int j = 0; j < 2; ++j) {
    const int base = lo + j * 128 + wid * 32;
    int nval = hi - base;
    nval = nval < 0 ? 0 : (nval > 32 ? 32 : nval);
    if (nval == 0) continue;            // wave-uniform

    const int mypage = bt[base + (lane & 31)];   // lane t<32 holds page[t]

    // ---- stage K tile: 16 independent 1KB loads in flight, then LDS writes
    float4 kreg[16];
#pragma unroll
    for (int i = 0; i < 16; ++i) {
      const int pg = __shfl(mypage, 2 * i + h5);
      kreg[i] = *(const float4*)(Kbase + (size_t)pg * KSTR + 4 * c5);
    }
#pragma unroll
    for (int i = 0; i < 16; ++i) {
      float* dst = &Kl[wid][2 * i + h5][4 * c5];
      dst[0] = kreg[i].x; dst[1] = kreg[i].y; dst[2] = kreg[i].z; dst[3] = kreg[i].w;
    }

    // ---- scores: rows {tq, tq+16} x 4 heads over quarter dq
    float s0[NG], s1[NG];
#pragma unroll
    for (int h = 0; h < NG; ++h) { s0[h] = 0.f; s1[h] = 0.f; }
#pragma unroll
    for (int si = 0; si < 16; ++si) {
      const int c8 = (dq << 4) | (si ^ dq);   // XOR order spreads banks
      const int o  = 2 * c8;
      const float k00 = Kl[wid][tq][o],      k01 = Kl[wid][tq][o + 1];
      const float k10 = Kl[wid][tq + 16][o], k11 = Kl[wid][tq + 16][o + 1];
#pragma unroll
      for (int h = 0; h < NG; ++h) {
        const float q0 = ql[h][o], q1 = ql[h][o + 1];
        s0[h] += k00 * q0 + k01 * q1;
        s1[h] += k10 * q0 + k11 * q1;
      }
    }
    // quad butterfly over dq (DPP-cheap)
#pragma unroll
    for (int h = 0; h < NG; ++h) {
      s0[h] += __shfl_xor(s0[h], 1); s0[h] += __shfl_xor(s0[h], 2);
      s1[h] += __shfl_xor(s1[h], 1); s1[h] += __shfl_xor(s1[h], 2);
    }
    // mask invalid rows
    const bool v0 = (tq < nval), v1 = (tq + 16 < nval);
#pragma unroll
    for (int h = 0; h < NG; ++h) {
      s0[h] = v0 ? s0[h] : -1e30f;
      s1[h] = v1 ? s1[h] : -1e30f;
    }
    // tile max (butterfly over tq; all lanes get result)
    float tm[NG];
#pragma unroll
    for (int h = 0; h < NG; ++h) tm[h] = fmaxf(s0[h], s1[h]);
#pragma unroll
    for (int mk = 4; mk <= 32; mk <<= 1)
#pragma unroll
      for (int h = 0; h < NG; ++h) tm[h] = fmaxf(tm[h], __shfl_xor(tm[h], mk));

    // online merge
    float sc[NG];
#pragma unroll
    for (int h = 0; h < NG; ++h) {
      const float Mn = fmaxf(M[h], tm[h]);
      sc[h] = __expf(M[h] - Mn);        // first tile: exp(-inf)=0
      M[h] = Mn;
    }
    // p + tile sums
    float p0[NG], p1[NG], ts[NG];
#pragma unroll
    for (int h = 0; h < NG; ++h) {
      p0[h] = __expf(s0[h] - M[h]);
      p1[h] = __expf(s1[h] - M[h]);
      ts[h] = p0[h] + p1[h];
    }
#pragma unroll
    for (int mk = 4; mk <= 32; mk <<= 1)
#pragma unroll
      for (int h = 0; h < NG; ++h) ts[h] += __shfl_xor(ts[h], mk);
#pragma unroll
    for (int h = 0; h < NG; ++h) Lr[h] = Lr[h] * sc[h] + ts[h];

    // write p (lanes dq==0 own rows tq, tq+16)
    if (dq == 0) {
      *(float4*)&Pl[wid][tq][0]      = make_float4(p0[0], p0[1], p0[2], p0[3]);
      *(float4*)&Pl[wid][tq + 16][0] = make_float4(p1[0], p1[1], p1[2], p1[3]);
    }

    // ---- PV: V direct from global; lane owns dv pair 2*lane
#pragma unroll
    for (int h = 0; h < NG; ++h) { acc2[h].x *= sc[h]; acc2[h].y *= sc[h]; }
#pragma unroll 4
    for (int t = 0; t < 32; ++t) {
      if (t >= nval) break;
      const int pg = __builtin_amdgcn_readlane(mypage, t);
      const float2 v2 = *(const float2*)(Vbase + (size_t)pg * KSTR);
      const float4 p4 = *(const float4*)&Pl[wid][t][0];
      acc2[0].x += p4.x * v2.x; acc2[0].y += p4.x * v2.y;
      acc2[1].x += p4.y * v2.x; acc2[1].y += p4.y * v2.y;
      acc2[2].x += p4.z * v2.x; acc2[2].y += p4.z * v2.y;
      acc2[3].x += p4.w * v2.x; acc2[3].y += p4.w * v2.y;
    }
  }

  // ---- merge 4 waves
  if (lane == 0) {
#pragma unroll
    for (int h = 0; h < NG; ++h) { Ml[wid][h] = M[h]; Ll[wid][h] = Lr[h]; }
  }
#pragma unroll
  for (int h = 0; h < NG; ++h) {
    Acc[wid][h][2 * lane]     = acc2[h].x;
    Acc[wid][h][2 * lane + 1] = acc2[h].y;
  }
  __syncthreads();

  if (tid < NG) {
    float Mf = -INFINITY;
    for (int w = 0; w < 4; ++w) Mf = fmaxf(Mf, Ml[w][tid]);
    float Lf = 0.f;
    for (int w = 0; w < 4; ++w) {
      const float mw = Ml[w][tid];
      if (mw > -INFINITY) Lf += Ll[w][tid] * __expf(mw - Mf);
    }
    Mg[tid] = Mf; Lg[tid] = Lf;
  }
  __syncthreads();

  for (int idx = tid; idx < NG * NDV; idx += 256) {
    const int g = idx >> 7;
    const int d = idx & (NDV - 1);
    const float Mf = Mg[g];
    const float Lf = Lg[g];
    float a = 0.f;
    for (int w = 0; w < 4; ++w) {
      const float mw = Ml[w][g];
      if (mw > -INFINITY) a += Acc[w][g][d] * __expf(mw - Mf);
    }
    ws_out[(pbase + g) * NDV + d] = (Lf > 0.f) ? (a / Lf) : 0.f;
    if (d == 0) ws_lse[pbase + g] = (Lf > 0.f) ? (Mf + __logf(Lf)) : -1e30f;
  }
}

// One block per (b,kvh,g); logsumexp-weighted combine over NPART partials.
__global__ __launch_bounds__(128) void attn_combine(
    const float* __restrict__ ws_out,
    const float* __restrict__ ws_lse,
    float* __restrict__ out)
{
  const int bkg = blockIdx.x;
  const int d   = threadIdx.x;

  float mg = -INFINITY;
#pragma unroll 16
  for (int p = 0; p < NPART; ++p)
    mg = fmaxf(mg, ws_lse[p * PSTRIDE + bkg]);

  float denom = 0.f, acc = 0.f;
#pragma unroll 8
  for (int p = 0; p < NPART; ++p) {
    const float e = __expf(ws_lse[p * PSTRIDE + bkg] - mg);
    denom += e;
    acc += e * ws_out[((size_t)p * PSTRIDE + bkg) * NDV + d];
  }
  out[(size_t)bkg * NDV + d] = acc / denom;
}

extern "C" void kernel_launch(void* const* d_in, const int* in_sizes, int n_in,
                              void* d_out, int out_size, void* d_ws, size_t ws_size,
                              hipStream_t stream) {
  const float* q        = (const float*)d_in[0];
  const float* k_cache  = (const float*)d_in[1];
  const float* v_cache  = (const float*)d_in[2];
  const int*   kv_lens  = (const int*)d_in[3];
  const int*   bt       = (const int*)d_in[4];
  float* out = (float*)d_out;

  float* ws_out = (float*)d_ws;                                  // 8.39 MB
  float* ws_lse = ws_out + (size_t)NPART * PSTRIDE * NDV;        // +64 KB

  attn_partial<<<NR * NB * NKVH * NSP, 256, 0, stream>>>(
      q, k_cache, v_cache, kv_lens, bt, ws_out, ws_lse);
  attn_combine<<<NB * NKVH * NG, NDV, 0, stream>>>(ws_out, ws_lse, out);
}

// Round 4
// 103.947 us; speedup vs baseline: 2.2777x; 2.2777x over previous
//
#include <hip/hip_runtime.h>
#include <math.h>

#define NR 8
#define NB 8
#define NH 32
#define NKVH 8
#define NG 4
#define ND 128
#define NDV 128
#define NPAGE 2048
#define CCHUNK 256
#define NSP 8                 // chunks per (r,b): 2048/256
#define NPART (NR*NSP)        // 64 partials
#define KSTR (NKVH*ND)        // 1024 floats per page
#define PSTRIDE (NB*NKVH*NG)  // 2048 rows per partial slot
#define QSCALE 0.088388347648318447f

__global__ __launch_bounds__(256, 4) void attn_partial(
    const float* __restrict__ q,
    const float* __restrict__ k_cache,
    const float* __restrict__ v_cache,
    const int* __restrict__ kv_lens,
    const int* __restrict__ block_table,
    float* __restrict__ ws_out,   // [NPART][NB][NKVH][NG][NDV]
    float* __restrict__ ws_lse)   // [NPART][NB][NKVH][NG]
{
  // XCD swizzle: bid%8 == r  -> each rank's 16MB gather pinned to one XCD L2.
  // kvh fastest within a rank -> the 8 disjoint 512B slices of the same 4KB
  // page are in flight together (DRAM row locality).
  const int bid  = blockIdx.x;
  const int r    = bid & 7;
  const int rest = bid >> 3;
  const int kvh  = rest & 7;
  const int b    = (rest >> 3) & 7;
  const int sp   = rest >> 6;

  const int tid   = threadIdx.x;
  const int wid   = tid >> 6;
  const int lane  = tid & 63;
  const int c     = lane & 15;    // dim-slice owner: dims 8c..8c+7
  const int tslot = lane >> 4;    // token slot within a 4-token pass

  const int len = kv_lens[r * NB + b];
  const int lo  = sp * CCHUNK;
  const int pi  = r * NSP + sp;
  const size_t pbase = (((size_t)pi * NB + b) * NKVH + kvh) * NG;

  if (lo >= len) {                 // empty chunk: sentinel, uniform exit
    if (tid < NG) ws_lse[pbase + tid] = -1e30f;
    return;
  }
  const int hi = min(len, lo + CCHUNK);

  // wave tile: 64 tokens
  const int base = lo + wid * 64;
  const int nval = min(max(hi - base, 0), 64);

  const int* bt = block_table + (r * NB + b) * NPAGE;
  const float* Kb = k_cache + (size_t)r * NPAGE * KSTR + kvh * ND  + 8 * c;
  const float* Vb = v_cache + (size_t)r * NPAGE * KSTR + kvh * NDV + 8 * c;

  // q fragments (dims 8c..8c+7 of each head), pre-scaled
  float4 qa[NG], qb_[NG];
  {
    const float* qp = q + (size_t)(b * NH + kvh * NG) * ND + 8 * c;
#pragma unroll
    for (int h = 0; h < NG; ++h) {
      float4 t0 = *(const float4*)(qp + h * ND);
      float4 t1 = *(const float4*)(qp + h * ND + 4);
      t0.x *= QSCALE; t0.y *= QSCALE; t0.z *= QSCALE; t0.w *= QSCALE;
      t1.x *= QSCALE; t1.y *= QSCALE; t1.z *= QSCALE; t1.w *= QSCALE;
      qa[h] = t0; qb_[h] = t1;
    }
  }

  float m[NG], l[NG];
  float4 a0[NG], a1[NG];           // acc for dv dims 8c..8c+3 / 8c+4..8c+7
#pragma unroll
  for (int h = 0; h < NG; ++h) {
    m[h] = -INFINITY; l[h] = 0.f;
    a0[h] = make_float4(0.f, 0.f, 0.f, 0.f);
    a1[h] = make_float4(0.f, 0.f, 0.f, 0.f);
  }

  // page-id preload: lane t holds page of token base+t (always in-bounds)
  const int mypage = bt[base + lane];

  const int npass = (nval + 3) >> 2;
#pragma unroll 2
  for (int p = 0; p < npass; ++p) {
    const int t  = 4 * p + tslot;
    const int pg = __shfl(mypage, t);          // per-lane src index
    const float* kp = Kb + (size_t)pg * KSTR;
    const float* vp = Vb + (size_t)pg * KSTR;
    const float4 k0 = *(const float4*)(kp);
    const float4 k1 = *(const float4*)(kp + 4);
    const float4 v0 = *(const float4*)(vp);
    const float4 v1 = *(const float4*)(vp + 4);

    // partial dot over this lane's 8 dims, all 4 heads
    float sh[NG];
#pragma unroll
    for (int h = 0; h < NG; ++h) {
      sh[h] = k0.x * qa[h].x + k0.y * qa[h].y + k0.z * qa[h].z + k0.w * qa[h].w
            + k1.x * qb_[h].x + k1.y * qb_[h].y + k1.z * qb_[h].z + k1.w * qb_[h].w;
    }
    // butterfly over the 16 dim-lanes; one instr serves all 4 tokens
#pragma unroll
    for (int mk = 1; mk <= 8; mk <<= 1) {
#pragma unroll
      for (int h = 0; h < NG; ++h) sh[h] += __shfl_xor(sh[h], mk);
    }

    if (t < nval) {                 // uniform within each 16-lane group
#pragma unroll
      for (int h = 0; h < NG; ++h) {
        const float s = sh[h];
        if (s > m[h]) {             // rescale path (decaying frequency)
          const float sc = __expf(m[h] - s);
          m[h] = s;
          l[h] = l[h] * sc + 1.0f;
          a0[h].x = a0[h].x * sc + v0.x; a0[h].y = a0[h].y * sc + v0.y;
          a0[h].z = a0[h].z * sc + v0.z; a0[h].w = a0[h].w * sc + v0.w;
          a1[h].x = a1[h].x * sc + v1.x; a1[h].y = a1[h].y * sc + v1.y;
          a1[h].z = a1[h].z * sc + v1.z; a1[h].w = a1[h].w * sc + v1.w;
        } else {
          const float d = __expf(s - m[h]);
          l[h] += d;
          a0[h].x += d * v0.x; a0[h].y += d * v0.y;
          a0[h].z += d * v0.z; a0[h].w += d * v0.w;
          a1[h].x += d * v1.x; a1[h].y += d * v1.y;
          a1[h].z += d * v1.z; a1[h].w += d * v1.w;
        }
      }
    }
  }

  // ---- merge the 4 token-slots (lanes 16 apart) ----
#pragma unroll
  for (int mk = 16; mk <= 32; mk <<= 1) {
#pragma unroll
    for (int h = 0; h < NG; ++h) {
      const float mo  = __shfl_xor(m[h], mk);
      const float lo_ = __shfl_xor(l[h], mk);
      const float Mn  = fmaxf(m[h], mo);
      const float sa  = (m[h] > -INFINITY) ? __expf(m[h] - Mn) : 0.f;
      const float sb  = (mo   > -INFINITY) ? __expf(mo   - Mn) : 0.f;
      l[h] = l[h] * sa + lo_ * sb;
      float4 o0, o1;
      o0.x = __shfl_xor(a0[h].x, mk); o0.y = __shfl_xor(a0[h].y, mk);
      o0.z = __shfl_xor(a0[h].z, mk); o0.w = __shfl_xor(a0[h].w, mk);
      o1.x = __shfl_xor(a1[h].x, mk); o1.y = __shfl_xor(a1[h].y, mk);
      o1.z = __shfl_xor(a1[h].z, mk); o1.w = __shfl_xor(a1[h].w, mk);
      a0[h].x = a0[h].x * sa + o0.x * sb; a0[h].y = a0[h].y * sa + o0.y * sb;
      a0[h].z = a0[h].z * sa + o0.z * sb; a0[h].w = a0[h].w * sa + o0.w * sb;
      a1[h].x = a1[h].x * sa + o1.x * sb; a1[h].y = a1[h].y * sa + o1.y * sb;
      a1[h].z = a1[h].z * sa + o1.z * sb; a1[h].w = a1[h].w * sa + o1.w * sb;
      m[h] = Mn;
    }
  }

  // ---- cross-wave merge via LDS ----
  __shared__ float Ml[4][NG], Ll[4][NG];
  __shared__ float Acc[4][NG][NDV];
  __shared__ float Mg[NG], Lg[NG];
  if (lane == 0) {
#pragma unroll
    for (int h = 0; h < NG; ++h) { Ml[wid][h] = m[h]; Ll[wid][h] = l[h]; }
  }
  if (tslot == 0) {
#pragma unroll
    for (int h = 0; h < NG; ++h) {
      *(float4*)&Acc[wid][h][8 * c]     = a0[h];
      *(float4*)&Acc[wid][h][8 * c + 4] = a1[h];
    }
  }
  __syncthreads();

  if (tid < NG) {
    float Mf = -INFINITY;
    for (int w = 0; w < 4; ++w) Mf = fmaxf(Mf, Ml[w][tid]);
    float Lf = 0.f;
    for (int w = 0; w < 4; ++w) {
      const float mw = Ml[w][tid];
      if (mw > -INFINITY) Lf += Ll[w][tid] * __expf(mw - Mf);
    }
    Mg[tid] = Mf; Lg[tid] = Lf;
  }
  __syncthreads();

  for (int idx = tid; idx < NG * NDV; idx += 256) {
    const int g = idx >> 7;
    const int d = idx & (NDV - 1);
    const float Mf = Mg[g];
    const float Lf = Lg[g];
    float a = 0.f;
    for (int w = 0; w < 4; ++w) {
      const float mw = Ml[w][g];
      if (mw > -INFINITY) a += Acc[w][g][d] * __expf(mw - Mf);
    }
    ws_out[(pbase + g) * NDV + d] = (Lf > 0.f) ? (a / Lf) : 0.f;
    if (d == 0) ws_lse[pbase + g] = (Lf > 0.f) ? (Mf + __logf(Lf)) : -1e30f;
  }
}

// One block per (b,kvh,g); logsumexp-weighted combine over NPART partials.
__global__ __launch_bounds__(128) void attn_combine(
    const float* __restrict__ ws_out,
    const float* __restrict__ ws_lse,
    float* __restrict__ out)
{
  const int bkg = blockIdx.x;
  const int d   = threadIdx.x;

  float mg = -INFINITY;
#pragma unroll 16
  for (int p = 0; p < NPART; ++p)
    mg = fmaxf(mg, ws_lse[p * PSTRIDE + bkg]);

  float denom = 0.f, acc = 0.f;
#pragma unroll 8
  for (int p = 0; p < NPART; ++p) {
    const float e = __expf(ws_lse[p * PSTRIDE + bkg] - mg);
    denom += e;
    acc += e * ws_out[((size_t)p * PSTRIDE + bkg) * NDV + d];
  }
  out[(size_t)bkg * NDV + d] = acc / denom;
}

extern "C" void kernel_launch(void* const* d_in, const int* in_sizes, int n_in,
                              void* d_out, int out_size, void* d_ws, size_t ws_size,
                              hipStream_t stream) {
  const float* q        = (const float*)d_in[0];
  const float* k_cache  = (const float*)d_in[1];
  const float* v_cache  = (const float*)d_in[2];
  const int*   kv_lens  = (const int*)d_in[3];
  const int*   bt       = (const int*)d_in[4];
  float* out = (float*)d_out;

  float* ws_out = (float*)d_ws;                                  // 8.39 MB
  float* ws_lse = ws_out + (size_t)NPART * PSTRIDE * NDV;        // +64 KB

  attn_partial<<<NR * NB * NKVH * NSP, 256, 0, stream>>>(
      q, k_cache, v_cache, kv_lens, bt, ws_out, ws_lse);
  attn_combine<<<NB * NKVH * NG, NDV, 0, stream>>>(ws_out, ws_lse, out);
}